// Round 2
// baseline (11267.650 us; speedup 1.0000x reference)
//
#include <hip/hip_runtime.h>
#include <hip/hip_bf16.h>

// FARGAN vocoder. Sizes fixed by the reference:
#define SS      64
#define NSUB    4
#define LPREV   512
#define NF      193
#define NFRAMES 100
#define BATCH   64

// ---------- helpers ----------

__device__ __forceinline__ float bf2f(unsigned short u) {
    return __uint_as_float(((unsigned int)u) << 16);
}

// fp32 -> bf16 RNE
__device__ __forceinline__ unsigned short f2bf(float x) {
    unsigned int u = __float_as_uint(x);
    unsigned int r = (u + 0x7fffu + ((u >> 16) & 1u)) >> 16;
    return (unsigned short)r;
}

__device__ __forceinline__ float sigm(float x) {
    return 1.0f / (1.0f + expf(-x));
}

// scalar load, element index i, dtype per template
template<bool F32>
__device__ __forceinline__ float ld1(const void* p, int i) {
    if constexpr (F32) return ((const float*)p)[i];
    else               return bf2f(((const unsigned short*)p)[i]);
}

// dot of weight row (element offset `off` into W) with fp32 LDS vector.
// KK multiple of 4. 4 accumulator chains for ILP (1 wave/SIMD -> ILP-only hiding).
template<int KK, bool F32>
__device__ __forceinline__ float dotk(const void* W, int off, const float* x, float accin) {
    if constexpr (F32) {
        const float* w = (const float*)W + off;
        float a0 = accin, a1 = 0.f, a2 = 0.f, a3 = 0.f;
#pragma unroll
        for (int k = 0; k < KK / 4; ++k) {
            a0 = fmaf(w[4 * k + 0], x[4 * k + 0], a0);
            a1 = fmaf(w[4 * k + 1], x[4 * k + 1], a1);
            a2 = fmaf(w[4 * k + 2], x[4 * k + 2], a2);
            a3 = fmaf(w[4 * k + 3], x[4 * k + 3], a3);
        }
        return (a0 + a1) + (a2 + a3);
    } else {
        const unsigned int* w2 = (const unsigned int*)((const unsigned short*)W + off);
        float a0 = accin, a1 = 0.f, a2 = 0.f, a3 = 0.f;
#pragma unroll
        for (int k = 0; k < KK / 4; ++k) {
            unsigned int u0 = w2[2 * k];
            unsigned int u1 = w2[2 * k + 1];
            a0 = fmaf(__uint_as_float(u0 << 16),          x[4 * k + 0], a0);
            a1 = fmaf(__uint_as_float(u0 & 0xffff0000u), x[4 * k + 1], a1);
            a2 = fmaf(__uint_as_float(u1 << 16),          x[4 * k + 2], a2);
            a3 = fmaf(__uint_as_float(u1 & 0xffff0000u), x[4 * k + 3], a3);
        }
        return (a0 + a1) + (a2 + a3);
    }
}

// runtime-length dot (nelem even), 2 chains
template<bool F32>
__device__ __forceinline__ float dot_rt(const void* W, int off, const float* x, int nelem) {
    if constexpr (F32) {
        const float* w = (const float*)W + off;
        float a0 = 0.f, a1 = 0.f;
#pragma unroll 8
        for (int k = 0; k < nelem / 2; ++k) {
            a0 = fmaf(w[2 * k + 0], x[2 * k + 0], a0);
            a1 = fmaf(w[2 * k + 1], x[2 * k + 1], a1);
        }
        return a0 + a1;
    } else {
        const unsigned int* w2 = (const unsigned int*)((const unsigned short*)W + off);
        float a0 = 0.f, a1 = 0.f;
#pragma unroll 8
        for (int k = 0; k < nelem / 2; ++k) {
            unsigned int u = w2[k];
            a0 = fmaf(__uint_as_float(u << 16),          x[2 * k + 0], a0);
            a1 = fmaf(__uint_as_float(u & 0xffff0000u), x[2 * k + 1], a1);
        }
        return a0 + a1;
    }
}

// ---------- dtype detector ----------
// features[0, 192, f] (the period channel) holds values in [64, 300).
// Probe 50 of them interpreted as fp32: all in range  => inputs are fp32.
// If the buffer is really bf16, these byte offsets land in a ~N(0,1) feature
// row reinterpreted as floats -> probability of 50 hits is ~0.
__global__ void fargan_detect(const void* feats, int* flag) {
    const float* pf = (const float*)feats;
    int ok = 1;
    for (int f = 0; f < 50; ++f) {
        float v = pf[192 * NFRAMES + f];
        if (!(v >= 63.0f && v <= 301.0f)) { ok = 0; break; }
    }
    *flag = ok;   // 1 = fp32, 0 = bf16
}

// ---------- kernel 1: frame conv (parallel over B x FRAMES) ----------

template<bool F32>
__device__ __forceinline__ void conv_body(
    const void* __restrict__ feats, const void* __restrict__ gfeat,
    const void* __restrict__ Wc1, const void* __restrict__ Wc2,
    const void* __restrict__ Wc3, float* __restrict__ cbuf)
{
    int blk = blockIdx.x;
    int b = blk / NFRAMES, f = blk - b * NFRAMES;
    int t = threadIdx.x;
    __shared__ float xa[256], xb[256];

    float v;
    if (t < 192) v = ld1<F32>(feats, b * (NF * NFRAMES) + t * NFRAMES + f);
    else         v = ld1<F32>(gfeat, b * 64 + (t - 192));
    xa[t] = v;
    __syncthreads();

    float acc = dot_rt<F32>(Wc1, t * 256, xa, 256);
    xb[t] = tanhf(acc);
    __syncthreads();

    acc = dot_rt<F32>(Wc2, t * 256, xb, 256);
    xa[t] = tanhf(acc);
    __syncthreads();

    float a0 = dot_rt<F32>(Wc3, t * 256, xa, 256);
    float a1 = dot_rt<F32>(Wc3, (t + 256) * 256, xa, 256);
    float* co = cbuf + (b * NFRAMES + f) * 512;
    co[t]       = tanhf(a0);
    co[t + 256] = tanhf(a1);
}

__global__ __launch_bounds__(256) void fargan_conv(
    const void* feats, const void* gfeat,
    const void* Wc1, const void* Wc2, const void* Wc3,
    const int* flag, float* cbuf)
{
    if (*flag) conv_body<true>(feats, gfeat, Wc1, Wc2, Wc3, cbuf);
    else       conv_body<false>(feats, gfeat, Wc1, Wc2, Wc3, cbuf);
}

// ---------- kernel 2: sequential recurrence, one WG per batch row ----------

template<bool F32>
__device__ __forceinline__ void gru_glu(
    const void* __restrict__ Wih,   // (192,128)
    const void* __restrict__ Whh,   // (192,64)
    const void* __restrict__ Wg,    // (64,64)
    const float* in0,   // 64 (fw / o1 / o2)
    const float* ps,    // prev_sub 64
    float* s,           // state 64 (updated in place)
    float* o,           // glu output 64
    float* gates,       // scratch 256
    int t)
{
    if (t < 192) {
        float accI = dotk<64, F32>(Wih, t * 128, in0, 0.f);
        accI = dotk<64, F32>(Wih, t * 128 + 64, ps, accI);
        float accH = dotk<64, F32>(Whh, t * 64, s, 0.f);
        if (t < 128) gates[t] = accI + accH;            // r,z: ir+hr / iz+hz
        else { gates[t] = accI; gates[t + 64] = accH; } // n: keep hnew separate
    }
    __syncthreads();
    if (t < 64) {
        float r = sigm(gates[t]);
        float z = sigm(gates[64 + t]);
        float n = tanhf(gates[128 + t] + r * gates[192 + t]);
        s[t] = (1.0f - z) * n + z * s[t];
    }
    __syncthreads();
    if (t < 64) {
        float acc = dotk<64, F32>(Wg, t * 64, s, 0.f);
        o[t] = s[t] * sigm(acc);
    }
    __syncthreads();
}

template<bool F32>
__device__ __forceinline__ void seq_body(
    const void* __restrict__ feats, const void* __restrict__ prev_in,
    const void* __restrict__ Wfw,  const void* __restrict__ Wfwg,
    const void* __restrict__ Wih1, const void* __restrict__ Whh1,
    const void* __restrict__ Wih2, const void* __restrict__ Whh2,
    const void* __restrict__ Wih3, const void* __restrict__ Whh3,
    const void* __restrict__ Wg1,  const void* __restrict__ Wg2,
    const void* __restrict__ Wg3,
    const void* __restrict__ Wsg,  const void* __restrict__ Wsd,
    const void* __restrict__ Wout,
    const float* __restrict__ cbuf, void* __restrict__ outp)
{
    int b = blockIdx.x;
    int t = threadIdx.x;

    // prev window as 1024-entry ring: window = hist[(base..base+511)&1023];
    // new 64 samples land at (base+512..575)&1023 — never collides with live window.
    __shared__ float hist[1024];
    __shared__ float cat[388];     // [feat2s(128) | prev_sub(64) | lookback(68) | sfw(128)]
    __shared__ float sfwb[128];
    __shared__ float s1b[64], s2b[64], s3b[64];
    __shared__ float psb[64];
    __shared__ float gates[256];
    __shared__ float fwb[64], o1b[64], o2b[64], o3b[64];
    __shared__ float sdb[128], sob[128];
    __shared__ float vpre[64];

    for (int i = t; i < LPREV; i += 256) hist[i] = ld1<F32>(prev_in, b * LPREV + i);
    if (t < 64) { s1b[t] = 0.f; s2b[t] = 0.f; s3b[t] = 0.f; }
    if (t < 128) sfwb[t] = 0.f;
    __syncthreads();

    int base = 0;
    for (int f = 0; f < NFRAMES; ++f) {
        int period = (int)rintf(ld1<F32>(feats, b * (NF * NFRAMES) + (NF - 1) * NFRAMES + f));
        const float* crow = cbuf + (b * NFRAMES + f) * 512;

        for (int k = 0; k < NSUB; ++k) {
            if (t < 64) {
                float pv = hist[(base + 448 + t) & 1023];
                psb[t] = pv;
                cat[128 + t] = pv;
            }
            if (t < 68) {
                int idx = LPREV - period + t - 2;
                if (idx >= LPREV) idx -= period;
                cat[192 + t] = hist[(base + idx) & 1023];
            }
            if (t < 128) {
                float c = crow[t * 4 + k];   // subs[:, :, k] = c[b, 4j+k]
                cat[t] = c;
                cat[260 + t] = sfwb[t];      // OLD sfw
                sfwb[t] = c;                 // new sfw = feat2s
            }
            __syncthreads();

            // ---- fw pre: N=64, K=388 split over 4 lanes/row ----
            {
                int j = t >> 2, pq = t & 3;
                int start = pq * 98;                 // 98,98,98,94 elems (even)
                int ne = (pq == 3) ? 94 : 98;
                float acc = dot_rt<F32>(Wfw, j * 388 + start, cat + start, ne);
                acc += __shfl_xor(acc, 1);
                acc += __shfl_xor(acc, 2);
                if (pq == 0) vpre[j] = tanhf(acc);
            }
            __syncthreads();

            if (t < 64) {
                float acc = dotk<64, F32>(Wfwg, t * 64, vpre, 0.f);
                fwb[t] = vpre[t] * sigm(acc);
            }
            __syncthreads();

            gru_glu<F32>(Wih1, Whh1, Wg1, fwb, psb, s1b, o1b, gates, t);
            gru_glu<F32>(Wih2, Whh2, Wg2, o1b, psb, s2b, o2b, gates, t);
            gru_glu<F32>(Wih3, Whh3, Wg3, o2b, psb, s3b, o3b, gates, t);

            // ---- skip dense: N=128, K=320 segmented [o1|o2|o3|fw|ps] ----
            if (t < 128) {
                int r0 = t * 320;
                float acc = dotk<64, F32>(Wsd, r0,       o1b, 0.f);
                acc = dotk<64, F32>(Wsd, r0 + 64,  o2b, acc);
                acc = dotk<64, F32>(Wsd, r0 + 128, o3b, acc);
                acc = dotk<64, F32>(Wsd, r0 + 192, fwb, acc);
                acc = dotk<64, F32>(Wsd, r0 + 256, psb, acc);
                sdb[t] = tanhf(acc);
            }
            __syncthreads();

            if (t < 128) {
                float acc = dotk<128, F32>(Wsg, t * 128, sdb, 0.f);
                sob[t] = sdb[t] * sigm(acc);
            }
            __syncthreads();

            if (t < 64) {
                float acc = dotk<128, F32>(Wout, t * 128, sob, 0.f);
                float ov = tanhf(acc);
                hist[(base + 512 + t) & 1023] = ov;
                int oi = b * (NFRAMES * NSUB * SS) + f * (NSUB * SS) + k * SS + t;
                if constexpr (F32) ((float*)outp)[oi] = ov;
                else               ((unsigned short*)outp)[oi] = f2bf(ov);
            }
            __syncthreads();

            base += SS;
        }
    }
}

__global__ __launch_bounds__(256) void fargan_seq(
    const void* feats, const void* prev_in,
    const void* Wfw,  const void* Wfwg,
    const void* Wih1, const void* Whh1,
    const void* Wih2, const void* Whh2,
    const void* Wih3, const void* Whh3,
    const void* Wg1,  const void* Wg2,  const void* Wg3,
    const void* Wsg,  const void* Wsd,  const void* Wout,
    const int* flag, const float* cbuf, void* outp)
{
    if (*flag) seq_body<true >(feats, prev_in, Wfw, Wfwg, Wih1, Whh1, Wih2, Whh2,
                               Wih3, Whh3, Wg1, Wg2, Wg3, Wsg, Wsd, Wout, cbuf, outp);
    else       seq_body<false>(feats, prev_in, Wfw, Wfwg, Wih1, Whh1, Wih2, Whh2,
                               Wih3, Whh3, Wg1, Wg2, Wg3, Wsg, Wsd, Wout, cbuf, outp);
}

// ---------- launch ----------

extern "C" void kernel_launch(void* const* d_in, const int* in_sizes, int n_in,
                              void* d_out, int out_size, void* d_ws, size_t ws_size,
                              hipStream_t stream) {
    const void* feats = d_in[0];
    const void* gfeat = d_in[1];
    const void* prev  = d_in[2];
    const void* Wc1   = d_in[3];
    const void* Wc2   = d_in[4];
    const void* Wc3   = d_in[5];
    const void* Wfw   = d_in[6];
    const void* Wfwg  = d_in[7];
    const void* Wih1  = d_in[8];
    const void* Whh1  = d_in[9];
    const void* Wih2  = d_in[10];
    const void* Whh2  = d_in[11];
    const void* Wih3  = d_in[12];
    const void* Whh3  = d_in[13];
    const void* Wg1   = d_in[14];
    const void* Wg2   = d_in[15];
    const void* Wg3   = d_in[16];
    const void* Wsg   = d_in[17];
    const void* Wsd   = d_in[18];
    const void* Wout  = d_in[19];

    int*   flag = (int*)d_ws;                       // 1 int, offset 0
    float* cbuf = (float*)((char*)d_ws + 256);      // 64*100*512 fp32 = 13.1 MB

    fargan_detect<<<1, 1, 0, stream>>>(feats, flag);
    fargan_conv<<<BATCH * NFRAMES, 256, 0, stream>>>(feats, gfeat, Wc1, Wc2, Wc3, flag, cbuf);
    fargan_seq<<<BATCH, 256, 0, stream>>>(feats, prev, Wfw, Wfwg,
                                          Wih1, Whh1, Wih2, Whh2, Wih3, Whh3,
                                          Wg1, Wg2, Wg3, Wsg, Wsd, Wout,
                                          flag, cbuf, d_out);
}